// Round 5
// baseline (699.782 us; speedup 1.0000x reference)
//
#include <hip/hip_runtime.h>
#include <cstdint>
#include <cstddef>

// Problem constants (match reference)
#define B_ 256
#define T_ 128
#define I_ 512
#define H_ 1024
#define O_ 512
static constexpr float ALPHA = 1.0f / 20.0f;   // DT/TAU
static constexpr float THR   = 1.0f;
static constexpr float S12   = 0.000244140625f; // 2^-12 (exact)

typedef _Float16 f16;
typedef __attribute__((ext_vector_type(8))) _Float16 f16x8;
typedef __attribute__((ext_vector_type(4))) float f32x4;

// ---------------------------------------------------------------------------
// fp32 tiled GEMM (fallback path only)
// ---------------------------------------------------------------------------
template<bool PERM_X, bool RELU>
__global__ __launch_bounds__(256)
void gemm128(const float* __restrict__ A, const float* __restrict__ Bw,
             const float* __restrict__ bias, float* __restrict__ C,
             int M, int N, int K) {
    constexpr int BM = 128, BN = 128, BK = 16, TM = 8, TN = 8;
    __shared__ float As[BK][BM];
    __shared__ float Bs[BK][BN + 4];

    const int tid = threadIdx.x;
    const int ntile = N / BN;
    const int bx = blockIdx.x % ntile;
    const int by = blockIdx.x / ntile;
    const int row0 = by * BM, col0 = bx * BN;
    const int tx = tid & 15;
    const int ty = tid >> 4;

    float acc[TM][TN] = {};

    for (int k0 = 0; k0 < K; k0 += BK) {
#pragma unroll
        for (int p = 0; p < 2; ++p) {
            int f = tid + p * 256;
            int r  = f >> 2;
            int kc = (f & 3) << 2;
            int m = row0 + r;
            const float* arow;
            if (PERM_X) {
                int t = m >> 8;
                int b = m & 255;
                arow = A + (size_t)(b * T_ + t) * K;
            } else {
                arow = A + (size_t)m * K;
            }
            float4 v = *reinterpret_cast<const float4*>(arow + k0 + kc);
            As[kc + 0][r] = v.x;
            As[kc + 1][r] = v.y;
            As[kc + 2][r] = v.z;
            As[kc + 3][r] = v.w;
        }
#pragma unroll
        for (int p = 0; p < 2; ++p) {
            int f = tid + p * 256;
            int r  = f >> 5;
            int nc = (f & 31) << 2;
            float4 v = *reinterpret_cast<const float4*>(Bw + (size_t)(k0 + r) * N + col0 + nc);
            *reinterpret_cast<float4*>(&Bs[r][nc]) = v;
        }
        __syncthreads();

#pragma unroll
        for (int k = 0; k < BK; ++k) {
            float a[TM], b[TN];
#pragma unroll
            for (int i = 0; i < TM; ++i) a[i] = As[k][ty * TM + i];
#pragma unroll
            for (int j = 0; j < TN; ++j) b[j] = Bs[k][tx * TN + j];
#pragma unroll
            for (int i = 0; i < TM; ++i)
#pragma unroll
                for (int j = 0; j < TN; ++j)
                    acc[i][j] += a[i] * b[j];
        }
        __syncthreads();
    }

#pragma unroll
    for (int i = 0; i < TM; ++i) {
        size_t m = (size_t)(row0 + ty * TM + i);
#pragma unroll
        for (int jj = 0; jj < TN; jj += 4) {
            int n = col0 + tx * TN + jj;
            float4 c4;
            float c0 = acc[i][jj + 0] + bias[n + 0];
            float c1 = acc[i][jj + 1] + bias[n + 1];
            float c2 = acc[i][jj + 2] + bias[n + 2];
            float c3 = acc[i][jj + 3] + bias[n + 3];
            if (RELU) {
                c0 = fmaxf(c0, 0.f); c1 = fmaxf(c1, 0.f);
                c2 = fmaxf(c2, 0.f); c3 = fmaxf(c3, 0.f);
            }
            c4.x = c0; c4.y = c1; c4.z = c2; c4.w = c3;
            *reinterpret_cast<float4*>(C + m * N + n) = c4;
        }
    }
}

// ---------------------------------------------------------------------------
// Fused fp16-MFMA GEMM + LIF time-scan (8-wave / 512-thread version).
//   pre[t][n] = A @ (Bhi + 2^-12 Blo) + bias   (SPLITX: + 2^-12 A1@Bhi term)
//   then (optional ReLU), then LIF scan over t; writes ONLY spikes.
// One block = ALL 128 timesteps of ONE batch element x 128 features.
//   Grid: blockIdx.x = bx * B_ + b  (bx outer -> weight tile L2-resident,
//         A rows read exactly once across the grid)
// 8 waves as 2(wr) x 4(wc); per-wave output 64 rows x 32 cols; BK=32.
// Per-thread acc: 2 groups x 4mi x 2ni x f32x4 = 64 VGPR -> fits 128-cap
// at __launch_bounds__(512,4) => 2 blocks/CU = 16 waves/CU.
// Epilogue: two-phase transpose/scan through Cs[64][132] (33.8 KB LDS union).
// ---------------------------------------------------------------------------
__device__ inline void gload_lds16(const void* gsrc, void* ldsdst) {
    __builtin_amdgcn_global_load_lds(
        (const __attribute__((address_space(1))) unsigned int*)gsrc,
        (__attribute__((address_space(3))) unsigned int*)ldsdst, 16, 0, 0);
}

template<bool SPLITX, bool PERM, bool RELU, bool WRITE_LAST>
__global__ __launch_bounds__(512, 4)
void gemm_lif(const float* __restrict__ A,
              const f16* __restrict__ Bhi,   // [N][K]
              const f16* __restrict__ Blo,   // [N][K] (x 2^12)
              const float* __restrict__ bias,
              float* __restrict__ S,         // [T][B][N] spikes out
              float* __restrict__ last_out,  // [B][N] (WRITE_LAST)
              int N, int K) {
    constexpr int BK = 32;
    // union: staging (Ah 8K | Bh 8K | Bl 8K | Al 8K) vs Cs[64][132] f32 (33.8K)
    __shared__ __align__(16) char smem[64 * 132 * 4];
    f16* Ah = (f16*)smem;            // 4096 f16
    f16* Bh = Ah + 4096;
    f16* Bl = Bh + 4096;
    f16* Al = Bl + 4096;             // used only when SPLITX
    float (*Cs)[132] = (float (*)[132])smem;

    const int tid  = threadIdx.x;
    const int lane = tid & 63;
    const int w    = tid >> 6;            // wave 0..7
    const int wr   = w >> 2;              // 0..1 (row half)
    const int wc   = w & 3;               // 0..3 (col quarter)
    const int b    = blockIdx.x & 255;    // batch element (inner)
    const int bx   = blockIdx.x >> 8;     // feature tile (outer)
    const int col0 = bx << 7;

    f32x4 acc0[4][2], acc1[4][2];
#pragma unroll
    for (int mi = 0; mi < 4; ++mi)
#pragma unroll
        for (int ni = 0; ni < 2; ++ni) {
            acc0[mi][ni] = {0.f, 0.f, 0.f, 0.f};
            acc1[mi][ni] = {0.f, 0.f, 0.f, 0.f};
        }

    for (int k0 = 0; k0 < K; k0 += BK) {
        // --- stage B splits via global_load_lds: 8 x 1KiB chunks, 1/wave ---
        {
            int r  = w * 16 + (lane >> 2);         // n within tile
            int kq = lane & 3;                     // 16B quad along k
            size_t off = (size_t)(col0 + r) * K + k0 + kq * 8;
            gload_lds16(Bhi + off, &Bh[w * 512]);
            gload_lds16(Blo + off, &Bl[w * 512]);
        }
        // --- stage A rows (r = timestep): fp32 -> fp16 ---
#pragma unroll
        for (int p = 0; p < 2; ++p) {
            int c = tid + p * 512;       // 1024 float4 chunks
            int r = c >> 3;              // row (=t) 0..127
            int q = c & 7;               // float4 along k
            const float* arow;
            if (PERM) arow = A + (size_t)(b * T_ + r) * K;
            else      arow = A + (size_t)(r * B_ + b) * K;
            float4 v = *reinterpret_cast<const float4*>(arow + k0 + q * 4);
            union { f16 h[4]; uint2 u; } hi;
            hi.h[0] = (f16)v.x; hi.h[1] = (f16)v.y;
            hi.h[2] = (f16)v.z; hi.h[3] = (f16)v.w;
            *reinterpret_cast<uint2*>(&Ah[r * BK + q * 4]) = hi.u;
            if (SPLITX) {
                union { f16 h[4]; uint2 u; } lo;
                lo.h[0] = (f16)((v.x - (float)hi.h[0]) * 4096.0f);
                lo.h[1] = (f16)((v.y - (float)hi.h[1]) * 4096.0f);
                lo.h[2] = (f16)((v.z - (float)hi.h[2]) * 4096.0f);
                lo.h[3] = (f16)((v.w - (float)hi.h[3]) * 4096.0f);
                *reinterpret_cast<uint2*>(&Al[r * BK + q * 4]) = lo.u;
            }
        }
        __syncthreads();

        // --- fragments + MFMA (per wave: 64 rows x 32 cols) ---
        f16x8 ahi[4], alo[4];
#pragma unroll
        for (int mi = 0; mi < 4; ++mi) {
            int ar = (wr * 64 + mi * 16 + (lane & 15)) * BK + (lane >> 4) * 8;
            ahi[mi] = *reinterpret_cast<const f16x8*>(&Ah[ar]);
            if (SPLITX) alo[mi] = *reinterpret_cast<const f16x8*>(&Al[ar]);
        }
#pragma unroll
        for (int ni = 0; ni < 2; ++ni) {
            int br = (wc * 32 + ni * 16 + (lane & 15)) * BK + (lane >> 4) * 8;
            f16x8 bh = *reinterpret_cast<const f16x8*>(&Bh[br]);
            f16x8 bl = *reinterpret_cast<const f16x8*>(&Bl[br]);
#pragma unroll
            for (int mi = 0; mi < 4; ++mi) {
                acc0[mi][ni] = __builtin_amdgcn_mfma_f32_16x16x32_f16(
                    ahi[mi], bh, acc0[mi][ni], 0, 0, 0);
                acc1[mi][ni] = __builtin_amdgcn_mfma_f32_16x16x32_f16(
                    ahi[mi], bl, acc1[mi][ni], 0, 0, 0);
                if (SPLITX)
                    acc1[mi][ni] = __builtin_amdgcn_mfma_f32_16x16x32_f16(
                        alo[mi], bh, acc1[mi][ni], 0, 0, 0);
            }
        }
        __syncthreads();
    }

    // --- two-phase epilogue: transpose halves through Cs + LIF scan ---
    // C/D frag: col = lane&15, row = (lane>>4)*4 + r
    float v = 0.f, s = 0.f;
    float* Sp = S + (size_t)b * N + col0 + (tid & 127);
    const size_t tstride = (size_t)B_ * N;

    // Phase A: wr==0 waves dump rows 0..63
    if (wr == 0) {
#pragma unroll
        for (int ni = 0; ni < 2; ++ni) {
            int col = wc * 32 + ni * 16 + (lane & 15);
            float bv = bias[col0 + col];
#pragma unroll
            for (int mi = 0; mi < 4; ++mi) {
                int rowb = mi * 16 + ((lane >> 4) << 2);
#pragma unroll
                for (int r = 0; r < 4; ++r) {
                    float cv = acc0[mi][ni][r] + S12 * acc1[mi][ni][r] + bv;
                    if (RELU) cv = fmaxf(cv, 0.f);
                    Cs[rowb + r][col] = cv;
                }
            }
        }
    }
    __syncthreads();
    if (tid < 128) {
#pragma unroll 4
        for (int t = 0; t < 64; ++t) {
            float in = Cs[t][tid];
            v = v + (in - v) * ALPHA;
            bool sp = (v >= THR);
            s = sp ? 1.0f : 0.0f;
            Sp[(size_t)t * tstride] = s;
            v = sp ? 0.0f : v;
        }
    }
    __syncthreads();
    // Phase B: wr==1 waves dump rows 64..127
    if (wr == 1) {
#pragma unroll
        for (int ni = 0; ni < 2; ++ni) {
            int col = wc * 32 + ni * 16 + (lane & 15);
            float bv = bias[col0 + col];
#pragma unroll
            for (int mi = 0; mi < 4; ++mi) {
                int rowb = mi * 16 + ((lane >> 4) << 2);
#pragma unroll
                for (int r = 0; r < 4; ++r) {
                    float cv = acc0[mi][ni][r] + S12 * acc1[mi][ni][r] + bv;
                    if (RELU) cv = fmaxf(cv, 0.f);
                    Cs[rowb + r][col] = cv;
                }
            }
        }
    }
    __syncthreads();
    if (tid < 128) {
#pragma unroll 4
        for (int t = 64; t < 128; ++t) {
            float in = Cs[t - 64][tid];
            v = v + (in - v) * ALPHA;
            bool sp = (v >= THR);
            s = sp ? 1.0f : 0.0f;
            Sp[(size_t)t * tstride] = s;
            v = sp ? 0.0f : v;
        }
        if (WRITE_LAST) last_out[(size_t)b * N + col0 + tid] = s;
    }
}

// ---------------------------------------------------------------------------
// LIF time-scan (fallback path), in place; optionally writes last spikes.
// ---------------------------------------------------------------------------
__global__ __launch_bounds__(256)
void lif_scan(float* __restrict__ buf, int BH, float* __restrict__ last_out) {
    int j = blockIdx.x * 256 + threadIdx.x;
    if (j >= BH) return;
    float v = 0.f;
    float last = 0.f;
    for (int t = 0; t < T_; ++t) {
        size_t idx = (size_t)t * BH + j;
        float in = buf[idx];
        v = v + (in - v) * ALPHA;
        bool sp = (v >= THR);
        last = sp ? 1.0f : 0.0f;
        buf[idx] = last;
        v = sp ? 0.0f : v;
    }
    if (last_out) last_out[j] = last;
}

// ---------------------------------------------------------------------------
// Tiled f64-accumulation fold: Wf[h][o] = sum_k W2[h][k]*Wo[k][o]  (fp32 out)
// ---------------------------------------------------------------------------
__global__ __launch_bounds__(256)
void make_wf2(const float* __restrict__ W2, const float* __restrict__ Wo,
              float* __restrict__ Wf) {
    __shared__ float w2s[64][33];   // [k][h]
    __shared__ float wos[64][68];   // [k][o]
    const int tid = threadIdx.x;
    const int ht = blockIdx.x >> 3, ot = blockIdx.x & 7;
    const int h0 = ht * 32, o0 = ot * 64;
    const int th = tid >> 3;
    const int to = tid & 7;

    double acc[8] = {0, 0, 0, 0, 0, 0, 0, 0};

    for (int k0 = 0; k0 < H_; k0 += 64) {
#pragma unroll
        for (int p = 0; p < 2; ++p) {
            int f = tid + p * 256;
            int i = f >> 4;
            int j4 = (f & 15) << 2;
            float4 v = *reinterpret_cast<const float4*>(
                W2 + (size_t)(h0 + i) * H_ + k0 + j4);
            w2s[j4 + 0][i] = v.x; w2s[j4 + 1][i] = v.y;
            w2s[j4 + 2][i] = v.z; w2s[j4 + 3][i] = v.w;
        }
#pragma unroll
        for (int p = 0; p < 4; ++p) {
            int f = tid + p * 256;
            int r = f >> 4;
            int c4 = (f & 15) << 2;
            float4 v = *reinterpret_cast<const float4*>(
                Wo + (size_t)(k0 + r) * O_ + o0 + c4);
            wos[r][c4 + 0] = v.x; wos[r][c4 + 1] = v.y;
            wos[r][c4 + 2] = v.z; wos[r][c4 + 3] = v.w;
        }
        __syncthreads();

#pragma unroll 8
        for (int k = 0; k < 64; ++k) {
            double a = (double)w2s[k][th];
#pragma unroll
            for (int j = 0; j < 8; ++j)
                acc[j] += a * (double)wos[k][to * 8 + j];
        }
        __syncthreads();
    }
#pragma unroll
    for (int j = 0; j < 8; ++j)
        Wf[(size_t)(h0 + th) * O_ + o0 + to * 8 + j] = (float)acc[j];
}

// bf[o] = bo[o] + sum_h b2[h]*Wo[h][o]  (f64 accum)
__global__ __launch_bounds__(256)
void make_bf(const float* __restrict__ Wo, const float* __restrict__ b2,
             const float* __restrict__ bo, float* __restrict__ bf) {
    int o = blockIdx.x * 256 + threadIdx.x;
    if (o >= O_) return;
    double acc = (double)bo[o];
    for (int h = 0; h < H_; ++h)
        acc += (double)b2[h] * (double)Wo[(size_t)h * O_ + o];
    bf[o] = (float)acc;
}

// 2-term scaled fp16 split of W [K][N], written TRANSPOSED [N][K]:
//   W = hi + 2^-12 * lo  (lo stored x 2^12, stays fp16-normal)
__global__ __launch_bounds__(256)
void split_w16(const float* __restrict__ W, f16* __restrict__ hi,
               f16* __restrict__ lo, int K, int N) {
    int idx = blockIdx.x * 256 + threadIdx.x;     // idx = n*K + k
    if (idx >= K * N) return;
    int n = idx / K;
    int k = idx - n * K;
    float wv = W[(size_t)k * N + n];
    f16 h0 = (f16)wv;
    float r = (wv - (float)h0) * 4096.0f;
    f16 h1 = (f16)r;
    hi[idx] = h0; lo[idx] = h1;
}

// ---------------------------------------------------------------------------
extern "C" void kernel_launch(void* const* d_in, const int* in_sizes, int n_in,
                              void* d_out, int out_size, void* d_ws, size_t ws_size,
                              hipStream_t stream) {
    const float* x  = (const float*)d_in[0];
    const float* We = (const float*)d_in[1];
    const float* be = (const float*)d_in[2];
    const float* W1 = (const float*)d_in[3];
    const float* b1 = (const float*)d_in[4];
    const float* W2 = (const float*)d_in[5];
    const float* b2 = (const float*)d_in[6];
    const float* Wo = (const float*)d_in[7];
    const float* bo = (const float*)d_in[8];

    float* out = (float*)d_out;
    float* so_last = out;                              // [B, O]
    float* S1 = out + (size_t)B_ * O_;                 // [T, B, H]
    float* S2 = S1 + (size_t)T_ * B_ * H_;             // [T, B, H]
    float* SO = S2 + (size_t)T_ * B_ * H_;             // [T, B, O]

    const int TB = T_ * B_;
    dim3 blk(256);
    dim3 blk512(512);

    // ---- workspace layout (bytes) ----
    const size_t sz_we  = (size_t)I_ * H_ * 2;
    const size_t sz_w1  = (size_t)H_ * H_ * 2;
    const size_t sz_wf  = (size_t)H_ * O_ * 2;
    const size_t off_weh = 0;
    const size_t off_wel = off_weh + sz_we;
    const size_t off_w1h = off_wel + sz_we;
    const size_t off_w1l = off_w1h + sz_w1;
    const size_t off_wf32 = off_w1l + sz_w1;
    const size_t off_bf   = off_wf32 + (size_t)H_ * O_ * 4;
    const size_t off_wfh  = off_bf + (size_t)O_ * 4;
    const size_t off_wfl  = off_wfh + sz_wf;
    const size_t need     = off_wfl + sz_wf;           // ~10.1 MiB

    if (ws_size >= need) {
        char* ws = (char*)d_ws;
        f16*   weh = (f16*)(ws + off_weh);
        f16*   wel = (f16*)(ws + off_wel);
        f16*   w1h = (f16*)(ws + off_w1h);
        f16*   w1l = (f16*)(ws + off_w1l);
        float* Wf  = (float*)(ws + off_wf32);
        float* bf  = (float*)(ws + off_bf);
        f16*   wfh = (f16*)(ws + off_wfh);
        f16*   wfl = (f16*)(ws + off_wfl);

        // ---- prep (every call; deterministic) ----
        split_w16<<<dim3((I_ * H_ + 255) / 256), blk, 0, stream>>>(We, weh, wel, I_, H_);
        split_w16<<<dim3((H_ * H_ + 255) / 256), blk, 0, stream>>>(W1, w1h, w1l, H_, H_);
        make_wf2<<<dim3(256), blk, 0, stream>>>(W2, Wo, Wf);
        make_bf<<<dim3(2), blk, 0, stream>>>(Wo, b2, bo, bf);
        split_w16<<<dim3((H_ * O_ + 255) / 256), blk, 0, stream>>>(Wf, wfh, wfl, H_, O_);

        // ---- Layer 0: S1 = LIF(relu(x @ We + be))   (fused) ----
        gemm_lif<true, true, true, false><<<dim3((H_ / 128) * B_), blk512, 0, stream>>>(
            x, weh, wel, be, S1, nullptr, H_, I_);

        // ---- Layer 1: S2 = LIF(S1 @ W1 + b1)        (fused) ----
        gemm_lif<false, false, false, false><<<dim3((H_ / 128) * B_), blk512, 0, stream>>>(
            S1, w1h, w1l, b1, S2, nullptr, H_, H_);

        // ---- Layer 2: SO = LIF(S2 @ (W2@Wo) + bf), so_last = SO[T-1] ----
        gemm_lif<false, false, false, true><<<dim3((O_ / 128) * B_), blk512, 0, stream>>>(
            S2, wfh, wfl, bf, SO, so_last, O_, H_);
    } else {
        // ---- fallback: proven fp32 folded path (needs ~2.1 MiB ws) ----
        float* Wf = (float*)d_ws;
        float* bf = Wf + (size_t)H_ * O_;
        gemm128<true, true><<<dim3((TB / 128) * (H_ / 128)), blk, 0, stream>>>(
            x, We, be, S1, TB, H_, I_);
        lif_scan<<<dim3((B_ * H_ + 255) / 256), blk, 0, stream>>>(S1, B_ * H_, nullptr);
        gemm128<false, false><<<dim3((TB / 128) * (H_ / 128)), blk, 0, stream>>>(
            S1, W1, b1, S2, TB, H_, H_);
        lif_scan<<<dim3((B_ * H_ + 255) / 256), blk, 0, stream>>>(S2, B_ * H_, nullptr);
        make_wf2<<<dim3(256), blk, 0, stream>>>(W2, Wo, Wf);
        make_bf<<<dim3(2), blk, 0, stream>>>(Wo, b2, bo, bf);
        gemm128<false, false><<<dim3((TB / 128) * (O_ / 128)), blk, 0, stream>>>(
            S2, Wf, bf, SO, TB, O_, H_);
        lif_scan<<<dim3((B_ * O_ + 255) / 256), blk, 0, stream>>>(SO, B_ * O_, so_last);
    }
}

// Round 6
// 644.298 us; speedup vs baseline: 1.0861x; 1.0861x over previous
//
#include <hip/hip_runtime.h>
#include <cstdint>
#include <cstddef>

// Problem constants (match reference)
#define B_ 256
#define T_ 128
#define I_ 512
#define H_ 1024
#define O_ 512
static constexpr float ALPHA = 1.0f / 20.0f;   // DT/TAU
static constexpr float THR   = 1.0f;
static constexpr float S12   = 0.000244140625f; // 2^-12 (exact)

typedef _Float16 f16;
typedef __attribute__((ext_vector_type(8))) _Float16 f16x8;
typedef __attribute__((ext_vector_type(4))) float f32x4;

// ---------------------------------------------------------------------------
// fp32 tiled GEMM (fallback path only)
// ---------------------------------------------------------------------------
template<bool PERM_X, bool RELU>
__global__ __launch_bounds__(256)
void gemm128(const float* __restrict__ A, const float* __restrict__ Bw,
             const float* __restrict__ bias, float* __restrict__ C,
             int M, int N, int K) {
    constexpr int BM = 128, BN = 128, BK = 16, TM = 8, TN = 8;
    __shared__ float As[BK][BM];
    __shared__ float Bs[BK][BN + 4];

    const int tid = threadIdx.x;
    const int ntile = N / BN;
    const int bx = blockIdx.x % ntile;
    const int by = blockIdx.x / ntile;
    const int row0 = by * BM, col0 = bx * BN;
    const int tx = tid & 15;
    const int ty = tid >> 4;

    float acc[TM][TN] = {};

    for (int k0 = 0; k0 < K; k0 += BK) {
#pragma unroll
        for (int p = 0; p < 2; ++p) {
            int f = tid + p * 256;
            int r  = f >> 2;
            int kc = (f & 3) << 2;
            int m = row0 + r;
            const float* arow;
            if (PERM_X) {
                int t = m >> 8;
                int b = m & 255;
                arow = A + (size_t)(b * T_ + t) * K;
            } else {
                arow = A + (size_t)m * K;
            }
            float4 v = *reinterpret_cast<const float4*>(arow + k0 + kc);
            As[kc + 0][r] = v.x;
            As[kc + 1][r] = v.y;
            As[kc + 2][r] = v.z;
            As[kc + 3][r] = v.w;
        }
#pragma unroll
        for (int p = 0; p < 2; ++p) {
            int f = tid + p * 256;
            int r  = f >> 5;
            int nc = (f & 31) << 2;
            float4 v = *reinterpret_cast<const float4*>(Bw + (size_t)(k0 + r) * N + col0 + nc);
            *reinterpret_cast<float4*>(&Bs[r][nc]) = v;
        }
        __syncthreads();

#pragma unroll
        for (int k = 0; k < BK; ++k) {
            float a[TM], b[TN];
#pragma unroll
            for (int i = 0; i < TM; ++i) a[i] = As[k][ty * TM + i];
#pragma unroll
            for (int j = 0; j < TN; ++j) b[j] = Bs[k][tx * TN + j];
#pragma unroll
            for (int i = 0; i < TM; ++i)
#pragma unroll
                for (int j = 0; j < TN; ++j)
                    acc[i][j] += a[i] * b[j];
        }
        __syncthreads();
    }

#pragma unroll
    for (int i = 0; i < TM; ++i) {
        size_t m = (size_t)(row0 + ty * TM + i);
#pragma unroll
        for (int jj = 0; jj < TN; jj += 4) {
            int n = col0 + tx * TN + jj;
            float4 c4;
            float c0 = acc[i][jj + 0] + bias[n + 0];
            float c1 = acc[i][jj + 1] + bias[n + 1];
            float c2 = acc[i][jj + 2] + bias[n + 2];
            float c3 = acc[i][jj + 3] + bias[n + 3];
            if (RELU) {
                c0 = fmaxf(c0, 0.f); c1 = fmaxf(c1, 0.f);
                c2 = fmaxf(c2, 0.f); c3 = fmaxf(c3, 0.f);
            }
            c4.x = c0; c4.y = c1; c4.z = c2; c4.w = c3;
            *reinterpret_cast<float4*>(C + m * N + n) = c4;
        }
    }
}

// ---------------------------------------------------------------------------
// Fused fp16-MFMA GEMM + LIF time-scan, double-buffered / pipelined.
//   pre[t][n] = A @ (Bhi + 2^-12 Blo) + bias   (SPLITX: + 2^-12 A1@Bhi term)
//   then (optional ReLU), then LIF scan over t; writes ONLY spikes.
// One block = ALL 128 timesteps of ONE batch element x 128 features.
// 4 waves (2x2 of 64x64), BK=32, 16x16x32 f16 MFMA, 2 accumulator groups.
// K-loop pipeline (one barrier per K-step):
//   issue gload_lds B(next) + global float4 A(next)->regs
//   ds_read + MFMA on current buffer           (loads in flight underneath)
//   convert A regs -> ds_write next buffer     (after vmcnt wait)
//   __syncthreads
// Epilogue: two-phase transpose/scan through Cs[64][132] (33.8 KB, overlays
// the staging buffers).
// ---------------------------------------------------------------------------
__device__ inline void gload_lds16(const void* gsrc, void* ldsdst) {
    __builtin_amdgcn_global_load_lds(
        (const __attribute__((address_space(1))) unsigned int*)gsrc,
        (__attribute__((address_space(3))) unsigned int*)ldsdst, 16, 0, 0);
}

template<bool SPLITX, bool PERM, bool RELU, bool WRITE_LAST>
__global__ __launch_bounds__(256, 2)
void gemm_lif(const float* __restrict__ A,
              const f16* __restrict__ Bhi,   // [N][K]
              const f16* __restrict__ Blo,   // [N][K] (x 2^12)
              const float* __restrict__ bias,
              float* __restrict__ S,         // [T][B][N] spikes out
              float* __restrict__ last_out,  // [B][N] (WRITE_LAST)
              int N, int K) {
    constexpr int BK = 32;
    constexpr int NBUF = SPLITX ? 4 : 3;            // Ah, Bh, Bl, (Al)
    constexpr int BUFSTR = NBUF * 4096;             // f16 elems per buffer set
    constexpr size_t SMEM = (2 * BUFSTR * 2 > 64 * 132 * 4)
                                ? (size_t)(2 * BUFSTR * 2)
                                : (size_t)(64 * 132 * 4);
    __shared__ __align__(16) char smem[SMEM];
    f16* sm = (f16*)smem;
    float (*Cs)[132] = (float (*)[132])smem;

    const int tid  = threadIdx.x;
    const int lane = tid & 63;
    const int w    = tid >> 6;            // wave 0..3
    const int wr   = w >> 1, wc = w & 1;  // 2x2 wave grid, 64x64 each
    const int ntile = N >> 7;
    const int bx = blockIdx.x % ntile;    // feature tile (inner)
    const int b  = blockIdx.x / ntile;    // batch element (outer)
    const int col0 = bx << 7;

    f32x4 acc0[4][4], acc1[4][4];
#pragma unroll
    for (int mi = 0; mi < 4; ++mi)
#pragma unroll
        for (int ni = 0; ni < 4; ++ni) {
            acc0[mi][ni] = {0.f, 0.f, 0.f, 0.f};
            acc1[mi][ni] = {0.f, 0.f, 0.f, 0.f};
        }

    // ---- prologue: stage tile 0 into buffer 0 ----
    {
        f16* Ah0 = sm;
        f16* Bh0 = sm + 4096;
        f16* Bl0 = sm + 8192;
        f16* Al0 = sm + 12288;    // SPLITX only
#pragma unroll
        for (int p = 0; p < 2; ++p) {
            int chunk = w * 2 + p;
            int r  = chunk * 16 + (lane >> 2);
            int kq = lane & 3;
            size_t off = (size_t)(col0 + r) * K + kq * 8;
            gload_lds16(Bhi + off, Bh0 + chunk * 512);
            gload_lds16(Blo + off, Bl0 + chunk * 512);
        }
#pragma unroll
        for (int p = 0; p < 4; ++p) {
            int c = tid + p * 256;
            int r = c >> 3;
            int q = c & 7;
            const float* arow = PERM ? A + (size_t)(b * T_ + r) * K
                                     : A + (size_t)(r * B_ + b) * K;
            float4 v = *reinterpret_cast<const float4*>(arow + q * 4);
            union { f16 h[4]; uint2 u; } hi;
            hi.h[0] = (f16)v.x; hi.h[1] = (f16)v.y;
            hi.h[2] = (f16)v.z; hi.h[3] = (f16)v.w;
            *reinterpret_cast<uint2*>(&Ah0[r * BK + q * 4]) = hi.u;
            if (SPLITX) {
                union { f16 h[4]; uint2 u; } lo;
                lo.h[0] = (f16)((v.x - (float)hi.h[0]) * 4096.0f);
                lo.h[1] = (f16)((v.y - (float)hi.h[1]) * 4096.0f);
                lo.h[2] = (f16)((v.z - (float)hi.h[2]) * 4096.0f);
                lo.h[3] = (f16)((v.w - (float)hi.h[3]) * 4096.0f);
                *reinterpret_cast<uint2*>(&Al0[r * BK + q * 4]) = lo.u;
            }
        }
    }
    __syncthreads();

    const int NIT = K / BK;
    for (int it = 0; it < NIT; ++it) {
        const int cur = it & 1, nxt = cur ^ 1;
        const bool more = (it + 1 < NIT);
        const int k0n = (it + 1) * BK;

        f16* Ah_c = sm + cur * BUFSTR;
        f16* Bh_c = Ah_c + 4096;
        f16* Bl_c = Ah_c + 8192;
        f16* Al_c = Ah_c + 12288;
        f16* Ah_n = sm + nxt * BUFSTR;
        f16* Bh_n = Ah_n + 4096;
        f16* Bl_n = Ah_n + 8192;
        f16* Al_n = Ah_n + 12288;

        // --- issue next tile's loads (B direct-to-LDS, A into registers) ---
        float4 a4[4];
        if (more) {
#pragma unroll
            for (int p = 0; p < 2; ++p) {
                int chunk = w * 2 + p;
                int r  = chunk * 16 + (lane >> 2);
                int kq = lane & 3;
                size_t off = (size_t)(col0 + r) * K + k0n + kq * 8;
                gload_lds16(Bhi + off, Bh_n + chunk * 512);
                gload_lds16(Blo + off, Bl_n + chunk * 512);
            }
#pragma unroll
            for (int p = 0; p < 4; ++p) {
                int c = tid + p * 256;
                int r = c >> 3;
                int q = c & 7;
                const float* arow = PERM ? A + (size_t)(b * T_ + r) * K
                                         : A + (size_t)(r * B_ + b) * K;
                a4[p] = *reinterpret_cast<const float4*>(arow + k0n + q * 4);
            }
        }

        // --- compute on current buffer: 4 A-frags, 8 B-frags, 32(+16) MFMAs ---
        {
            f16x8 ahi[4], alo[4];
#pragma unroll
            for (int mi = 0; mi < 4; ++mi) {
                int ar = (wr * 64 + mi * 16 + (lane & 15)) * BK + (lane >> 4) * 8;
                ahi[mi] = *reinterpret_cast<const f16x8*>(&Ah_c[ar]);
                if (SPLITX) alo[mi] = *reinterpret_cast<const f16x8*>(&Al_c[ar]);
            }
#pragma unroll
            for (int ni = 0; ni < 4; ++ni) {
                int br = (wc * 64 + ni * 16 + (lane & 15)) * BK + (lane >> 4) * 8;
                f16x8 bh = *reinterpret_cast<const f16x8*>(&Bh_c[br]);
                f16x8 bl = *reinterpret_cast<const f16x8*>(&Bl_c[br]);
#pragma unroll
                for (int mi = 0; mi < 4; ++mi) {
                    acc0[mi][ni] = __builtin_amdgcn_mfma_f32_16x16x32_f16(
                        ahi[mi], bh, acc0[mi][ni], 0, 0, 0);
                    acc1[mi][ni] = __builtin_amdgcn_mfma_f32_16x16x32_f16(
                        ahi[mi], bl, acc1[mi][ni], 0, 0, 0);
                    if (SPLITX)
                        acc1[mi][ni] = __builtin_amdgcn_mfma_f32_16x16x32_f16(
                            alo[mi], bh, acc1[mi][ni], 0, 0, 0);
                }
            }
        }

        // --- late write: convert prefetched A regs into next buffer ---
        if (more) {
#pragma unroll
            for (int p = 0; p < 4; ++p) {
                int c = tid + p * 256;
                int r = c >> 3;
                int q = c & 7;
                float4 v = a4[p];
                union { f16 h[4]; uint2 u; } hi;
                hi.h[0] = (f16)v.x; hi.h[1] = (f16)v.y;
                hi.h[2] = (f16)v.z; hi.h[3] = (f16)v.w;
                *reinterpret_cast<uint2*>(&Ah_n[r * BK + q * 4]) = hi.u;
                if (SPLITX) {
                    union { f16 h[4]; uint2 u; } lo;
                    lo.h[0] = (f16)((v.x - (float)hi.h[0]) * 4096.0f);
                    lo.h[1] = (f16)((v.y - (float)hi.h[1]) * 4096.0f);
                    lo.h[2] = (f16)((v.z - (float)hi.h[2]) * 4096.0f);
                    lo.h[3] = (f16)((v.w - (float)hi.h[3]) * 4096.0f);
                    *reinterpret_cast<uint2*>(&Al_n[r * BK + q * 4]) = lo.u;
                }
            }
        }
        __syncthreads();
    }

    // --- two-phase epilogue: transpose halves through Cs + LIF scan ---
    // C/D frag: col = lane&15, row = (lane>>4)*4 + r
    float v = 0.f, s = 0.f;
    float* Sp = S + (size_t)b * N + col0 + (tid & 127);
    const size_t tstride = (size_t)B_ * N;

    if (wr == 0) {   // rows 0..63
#pragma unroll
        for (int ni = 0; ni < 4; ++ni) {
            int col = wc * 64 + ni * 16 + (lane & 15);
            float bv = bias[col0 + col];
#pragma unroll
            for (int mi = 0; mi < 4; ++mi) {
                int rowb = mi * 16 + ((lane >> 4) << 2);
#pragma unroll
                for (int r = 0; r < 4; ++r) {
                    float cv = acc0[mi][ni][r] + S12 * acc1[mi][ni][r] + bv;
                    if (RELU) cv = fmaxf(cv, 0.f);
                    Cs[rowb + r][col] = cv;
                }
            }
        }
    }
    __syncthreads();
    if (tid < 128) {
#pragma unroll 4
        for (int t = 0; t < 64; ++t) {
            float in = Cs[t][tid];
            v = v + (in - v) * ALPHA;
            bool sp = (v >= THR);
            s = sp ? 1.0f : 0.0f;
            Sp[(size_t)t * tstride] = s;
            v = sp ? 0.0f : v;
        }
    }
    __syncthreads();
    if (wr == 1) {   // rows 64..127
#pragma unroll
        for (int ni = 0; ni < 4; ++ni) {
            int col = wc * 64 + ni * 16 + (lane & 15);
            float bv = bias[col0 + col];
#pragma unroll
            for (int mi = 0; mi < 4; ++mi) {
                int rowb = mi * 16 + ((lane >> 4) << 2);
#pragma unroll
                for (int r = 0; r < 4; ++r) {
                    float cv = acc0[mi][ni][r] + S12 * acc1[mi][ni][r] + bv;
                    if (RELU) cv = fmaxf(cv, 0.f);
                    Cs[rowb + r][col] = cv;
                }
            }
        }
    }
    __syncthreads();
    if (tid < 128) {
#pragma unroll 4
        for (int t = 64; t < 128; ++t) {
            float in = Cs[t - 64][tid];
            v = v + (in - v) * ALPHA;
            bool sp = (v >= THR);
            s = sp ? 1.0f : 0.0f;
            Sp[(size_t)t * tstride] = s;
            v = sp ? 0.0f : v;
        }
        if (WRITE_LAST) last_out[(size_t)b * N + col0 + tid] = s;
    }
}

// ---------------------------------------------------------------------------
// LIF time-scan (fallback path), in place; optionally writes last spikes.
// ---------------------------------------------------------------------------
__global__ __launch_bounds__(256)
void lif_scan(float* __restrict__ buf, int BH, float* __restrict__ last_out) {
    int j = blockIdx.x * 256 + threadIdx.x;
    if (j >= BH) return;
    float v = 0.f;
    float last = 0.f;
    for (int t = 0; t < T_; ++t) {
        size_t idx = (size_t)t * BH + j;
        float in = buf[idx];
        v = v + (in - v) * ALPHA;
        bool sp = (v >= THR);
        last = sp ? 1.0f : 0.0f;
        buf[idx] = last;
        v = sp ? 0.0f : v;
    }
    if (last_out) last_out[j] = last;
}

// ---------------------------------------------------------------------------
// Tiled f64-accumulation fold: Wf[h][o] = sum_k W2[h][k]*Wo[k][o]  (fp32 out)
// ---------------------------------------------------------------------------
__global__ __launch_bounds__(256)
void make_wf2(const float* __restrict__ W2, const float* __restrict__ Wo,
              float* __restrict__ Wf) {
    __shared__ float w2s[64][33];   // [k][h]
    __shared__ float wos[64][68];   // [k][o]
    const int tid = threadIdx.x;
    const int ht = blockIdx.x >> 3, ot = blockIdx.x & 7;
    const int h0 = ht * 32, o0 = ot * 64;
    const int th = tid >> 3;
    const int to = tid & 7;

    double acc[8] = {0, 0, 0, 0, 0, 0, 0, 0};

    for (int k0 = 0; k0 < H_; k0 += 64) {
#pragma unroll
        for (int p = 0; p < 2; ++p) {
            int f = tid + p * 256;
            int i = f >> 4;
            int j4 = (f & 15) << 2;
            float4 v = *reinterpret_cast<const float4*>(
                W2 + (size_t)(h0 + i) * H_ + k0 + j4);
            w2s[j4 + 0][i] = v.x; w2s[j4 + 1][i] = v.y;
            w2s[j4 + 2][i] = v.z; w2s[j4 + 3][i] = v.w;
        }
#pragma unroll
        for (int p = 0; p < 4; ++p) {
            int f = tid + p * 256;
            int r = f >> 4;
            int c4 = (f & 15) << 2;
            float4 v = *reinterpret_cast<const float4*>(
                Wo + (size_t)(k0 + r) * O_ + o0 + c4);
            wos[r][c4 + 0] = v.x; wos[r][c4 + 1] = v.y;
            wos[r][c4 + 2] = v.z; wos[r][c4 + 3] = v.w;
        }
        __syncthreads();

#pragma unroll 8
        for (int k = 0; k < 64; ++k) {
            double a = (double)w2s[k][th];
#pragma unroll
            for (int j = 0; j < 8; ++j)
                acc[j] += a * (double)wos[k][to * 8 + j];
        }
        __syncthreads();
    }
#pragma unroll
    for (int j = 0; j < 8; ++j)
        Wf[(size_t)(h0 + th) * O_ + o0 + to * 8 + j] = (float)acc[j];
}

// bf[o] = bo[o] + sum_h b2[h]*Wo[h][o]  (f64 accum)
__global__ __launch_bounds__(256)
void make_bf(const float* __restrict__ Wo, const float* __restrict__ b2,
             const float* __restrict__ bo, float* __restrict__ bf) {
    int o = blockIdx.x * 256 + threadIdx.x;
    if (o >= O_) return;
    double acc = (double)bo[o];
    for (int h = 0; h < H_; ++h)
        acc += (double)b2[h] * (double)Wo[(size_t)h * O_ + o];
    bf[o] = (float)acc;
}

// 2-term scaled fp16 split of W [K][N], written TRANSPOSED [N][K]:
//   W = hi + 2^-12 * lo  (lo stored x 2^12, stays fp16-normal)
__global__ __launch_bounds__(256)
void split_w16(const float* __restrict__ W, f16* __restrict__ hi,
               f16* __restrict__ lo, int K, int N) {
    int idx = blockIdx.x * 256 + threadIdx.x;     // idx = n*K + k
    if (idx >= K * N) return;
    int n = idx / K;
    int k = idx - n * K;
    float wv = W[(size_t)k * N + n];
    f16 h0 = (f16)wv;
    float r = (wv - (float)h0) * 4096.0f;
    f16 h1 = (f16)r;
    hi[idx] = h0; lo[idx] = h1;
}

// ---------------------------------------------------------------------------
extern "C" void kernel_launch(void* const* d_in, const int* in_sizes, int n_in,
                              void* d_out, int out_size, void* d_ws, size_t ws_size,
                              hipStream_t stream) {
    const float* x  = (const float*)d_in[0];
    const float* We = (const float*)d_in[1];
    const float* be = (const float*)d_in[2];
    const float* W1 = (const float*)d_in[3];
    const float* b1 = (const float*)d_in[4];
    const float* W2 = (const float*)d_in[5];
    const float* b2 = (const float*)d_in[6];
    const float* Wo = (const float*)d_in[7];
    const float* bo = (const float*)d_in[8];

    float* out = (float*)d_out;
    float* so_last = out;                              // [B, O]
    float* S1 = out + (size_t)B_ * O_;                 // [T, B, H]
    float* S2 = S1 + (size_t)T_ * B_ * H_;             // [T, B, H]
    float* SO = S2 + (size_t)T_ * B_ * H_;             // [T, B, O]

    const int TB = T_ * B_;
    dim3 blk(256);

    // ---- workspace layout (bytes) ----
    const size_t sz_we  = (size_t)I_ * H_ * 2;
    const size_t sz_w1  = (size_t)H_ * H_ * 2;
    const size_t sz_wf  = (size_t)H_ * O_ * 2;
    const size_t off_weh = 0;
    const size_t off_wel = off_weh + sz_we;
    const size_t off_w1h = off_wel + sz_we;
    const size_t off_w1l = off_w1h + sz_w1;
    const size_t off_wf32 = off_w1l + sz_w1;
    const size_t off_bf   = off_wf32 + (size_t)H_ * O_ * 4;
    const size_t off_wfh  = off_bf + (size_t)O_ * 4;
    const size_t off_wfl  = off_wfh + sz_wf;
    const size_t need     = off_wfl + sz_wf;           // ~10.1 MiB

    if (ws_size >= need) {
        char* ws = (char*)d_ws;
        f16*   weh = (f16*)(ws + off_weh);
        f16*   wel = (f16*)(ws + off_wel);
        f16*   w1h = (f16*)(ws + off_w1h);
        f16*   w1l = (f16*)(ws + off_w1l);
        float* Wf  = (float*)(ws + off_wf32);
        float* bf  = (float*)(ws + off_bf);
        f16*   wfh = (f16*)(ws + off_wfh);
        f16*   wfl = (f16*)(ws + off_wfl);

        // ---- prep (every call; deterministic) ----
        split_w16<<<dim3((I_ * H_ + 255) / 256), blk, 0, stream>>>(We, weh, wel, I_, H_);
        split_w16<<<dim3((H_ * H_ + 255) / 256), blk, 0, stream>>>(W1, w1h, w1l, H_, H_);
        make_wf2<<<dim3(256), blk, 0, stream>>>(W2, Wo, Wf);
        make_bf<<<dim3(2), blk, 0, stream>>>(Wo, b2, bo, bf);
        split_w16<<<dim3((H_ * O_ + 255) / 256), blk, 0, stream>>>(Wf, wfh, wfl, H_, O_);

        // ---- Layer 0: S1 = LIF(relu(x @ We + be))   (fused, pipelined) ----
        gemm_lif<true, true, true, false><<<dim3(B_ * (H_ / 128)), blk, 0, stream>>>(
            x, weh, wel, be, S1, nullptr, H_, I_);

        // ---- Layer 1: S2 = LIF(S1 @ W1 + b1) ----
        gemm_lif<false, false, false, false><<<dim3(B_ * (H_ / 128)), blk, 0, stream>>>(
            S1, w1h, w1l, b1, S2, nullptr, H_, H_);

        // ---- Layer 2: SO = LIF(S2 @ (W2@Wo) + bf), so_last = SO[T-1] ----
        gemm_lif<false, false, false, true><<<dim3(B_ * (O_ / 128)), blk, 0, stream>>>(
            S2, wfh, wfl, bf, SO, so_last, O_, H_);
    } else {
        // ---- fallback: proven fp32 folded path (needs ~2.1 MiB ws) ----
        float* Wf = (float*)d_ws;
        float* bf = Wf + (size_t)H_ * O_;
        gemm128<true, true><<<dim3((TB / 128) * (H_ / 128)), blk, 0, stream>>>(
            x, We, be, S1, TB, H_, I_);
        lif_scan<<<dim3((B_ * H_ + 255) / 256), blk, 0, stream>>>(S1, B_ * H_, nullptr);
        gemm128<false, false><<<dim3((TB / 128) * (H_ / 128)), blk, 0, stream>>>(
            S1, W1, b1, S2, TB, H_, H_);
        lif_scan<<<dim3((B_ * H_ + 255) / 256), blk, 0, stream>>>(S2, B_ * H_, nullptr);
        make_wf2<<<dim3(256), blk, 0, stream>>>(W2, Wo, Wf);
        make_bf<<<dim3(2), blk, 0, stream>>>(Wo, b2, bo, bf);
        gemm128<false, false><<<dim3((TB / 128) * (O_ / 128)), blk, 0, stream>>>(
            S2, Wf, bf, SO, TB, O_, H_);
        lif_scan<<<dim3((B_ * O_ + 255) / 256), blk, 0, stream>>>(SO, B_ * O_, so_last);
    }
}